// Round 16
// baseline (39.700 us; speedup 1.0000x reference)
//
#include <hip/hip_runtime.h>
#include <hip/hip_fp16.h>

// AliasFreeActivation, round 16: r13 barrier-free wave-private units with the
// P1 load/compute split enforced by an IR-level compiler fence
// (asm volatile "" ::: "memory"), which loads cannot legally sink across.
// r14 (plain split) and r15 (sched_barrier) were both silently re-fused:
// VGPR_Count stayed 32. Success criterion this round: VGPR ~80-104.
// x (2,256,84,84) f32 -> up x4 (24t) -> lrelu -> down x2 (12t) -> crop 10
// -> out (2,256,148,148) f32.
//
// Unit = (plane pz, band b 0..9, chunk c 0..2) per wave64, private 1024-dw
// LDS slice, no __syncthreads. Band: out rows i0..i0+15, i0=min(16b,132)
// (band 9 overlaps band 8; duplicate stores bitwise-identical).
// Chunks: c0 g0..15 / out g8 0..6; c1 g14..29 / g8 7..13; c2 g28..38 / g8 14..18.
// LDS f16 layout: row r, 64 dwords; dword 4B+cc = half2(col 8B+cc, col 8B+4+cc).
// P1: phase A issues ALL 20 float2 global loads; compiler fence; phase B
//     24 pk-fma + pack + b128 store per task. One latency exposure per wave.
// P2: lane-per-dword fused up-v+lrelu+down-v, v2 f32 math, lane-local alias.
// P3: 14-dword row reads -> unpack -> packed down-h -> float4 stores.
// Cross-lane handoffs ordered by s_waitcnt lgkmcnt(0) (lockstep wave).

typedef float v2 __attribute__((ext_vector_type(2)));

constexpr int IN_HW  = 84;
constexpr int OUT_HW = 148;
constexpr float SLOPE = 0.2f;

__device__ __forceinline__ float rfl(float v) {
    return __uint_as_float(__builtin_amdgcn_readfirstlane(__float_as_uint(v)));
}
__device__ __forceinline__ unsigned pkv(v2 a) {
    __half2 h = __float22half2_rn(make_float2(a.x, a.y));
    union { __half2 h; unsigned u; } c; c.h = h; return c.u;
}
__device__ __forceinline__ v2 up16(unsigned u) {
    union { unsigned u; __half2 h; } c; c.u = u;
    float2 f = __half22float2(c.h);
    return (v2){f.x, f.y};
}
__device__ __forceinline__ void lds_fence() {
    asm volatile("s_waitcnt lgkmcnt(0)" ::: "memory");
}
__device__ __forceinline__ void compiler_fence() {
    asm volatile("" ::: "memory");     // IR-level: loads may not sink past this
}

template<int CHUNK>
__device__ __forceinline__ void wave_body(
    const float* __restrict__ xin, float* __restrict__ o,
    unsigned* __restrict__ S, int l, int i0, int IR0,
    const float* fu, const float* fd)
{
    constexpr int G0  = (CHUNK == 0) ? 0 : (CHUNK == 1) ? 14 : 28;
    constexpr int NG  = (CHUNK == 2) ? 11 : 16;   // input col-groups
    constexpr int GO8 = (CHUNK == 0) ? 0 : (CHUNK == 1) ? 7 : 14;
    constexpr int NG8 = (CHUNK == 2) ? 5 : 7;     // output col-groups
    constexpr int NT1 = 16 * NG;
    constexpr int NT3 = 16 * NG8;
    constexpr int K1  = (NT1 + 63) / 64;          // 4 (c0/c1) or 3 (c2)

    // ---- P1 phase A: issue ALL global loads, hold in registers ----
    float2 L0[K1], L1[K1], L2[K1], L3[K1], L4[K1];
#pragma unroll
    for (int k = 0; k < K1; ++k) {
        int t = l + 64 * k;
        if (t < NT1) {
            int r = t / NG, gl = t - r * NG, g = G0 + gl;
            const float* xr = xin + (IR0 + r) * IN_HW + 2 * g;
            L0[k] = *(const float2*)(xr);
            L1[k] = *(const float2*)(xr + 2);
            L2[k] = *(const float2*)(xr + 4);
            L3[k] = *(const float2*)(xr + 6);
            L4[k] = *(const float2*)(xr + ((g == 38) ? 6 : 8)); // OOB guard
        }
    }
    compiler_fence();                  // loads stay above; results live in VGPRs

    // ---- P1 phase B: FMAs + LDS stores ----
#pragma unroll
    for (int k = 0; k < K1; ++k) {
        int t = l + 64 * k;
        if (t < NT1) {
            int r = t / NG, gl = t - r * NG;
            float2 p0 = L0[k], p1 = L1[k], p2 = L2[k], p3 = L3[k], p4 = L4[k];
            v2 V0 = {p0.y, p1.x};
            v2 V1 = {p1.x, p1.y};
            v2 V2 = {p1.y, p2.x};
            v2 V3 = {p2.x, p2.y};
            v2 V4 = {p2.y, p3.x};
            v2 V5 = {p3.x, p3.y};
            v2 V6 = {p3.y, p4.x};   // .y garbage only for g=38 tail (unused cols)
            v2 AB0 = V5*fu[1] + V4*fu[5] + V3*fu[9]  + V2*fu[13] + V1*fu[17] + V0*fu[21];
            v2 AB1 = V5*fu[2] + V4*fu[6] + V3*fu[10] + V2*fu[14] + V1*fu[18] + V0*fu[22];
            v2 AB2 = V5*fu[3] + V4*fu[7] + V3*fu[11] + V2*fu[15] + V1*fu[19] + V0*fu[23];
            v2 AB3 = V6*fu[0] + V5*fu[4] + V4*fu[8]  + V3*fu[12] + V2*fu[16] + V1*fu[20];
            uint4 pk;
            pk.x = pkv(AB0); pk.y = pkv(AB1); pk.z = pkv(AB2); pk.w = pkv(AB3);
            *(uint4*)(S + r * 64 + 4 * gl) = pk;
        }
    }
    lds_fence();                       // P1 writes visible to all lanes

    // ---- P2: lane-per-dword fused up-v + lrelu + down-v (v2 f32) ----
    {
        const unsigned* up = S + l;
        v2 colv[16];
#pragma unroll
        for (int r = 0; r < 16; ++r) colv[r] = up16(up[r * 64]);
        v2 acc[16];
#pragma unroll
        for (int i = 0; i < 16; ++i) acc[i] = (v2)(0.0f);
#pragma unroll
        for (int t = 0; t < 42; ++t) {
            const int n  = (t + 1) >> 2;
            const int ph = (t + 1) & 3;
            v2 z = colv[n+5] * fu[ph];
            z += colv[n+4] * fu[ph+4];
            z += colv[n+3] * fu[ph+8];
            z += colv[n+2] * fu[ph+12];
            z += colv[n+1] * fu[ph+16];
            z += colv[n]   * fu[ph+20];
            z = __builtin_elementwise_max(z, z * SLOPE);   // lrelu
            const int m = t >> 1;
#pragma unroll
            for (int k = 0; k < 6; ++k) {                  // static after unroll
                const int li = m - k;
                if (li >= 0 && li < 16)
                    acc[li] += z * fd[(t & 1) ? (10 - 2*k) : (11 - 2*k)];
            }
        }
        unsigned* tvc = S + l;          // same dwords this lane read: no hazard
#pragma unroll
        for (int i = 0; i < 16; ++i) tvc[i * 64] = pkv(acc[i]);
    }
    lds_fence();                       // P2 writes visible to all lanes

    // ---- P3: horizontal down-conv + store ----
#pragma unroll
    for (int k = 0; k < 2; ++k) {
        int t = l + 64 * k;
        if (t < NT3) {
            int i = t / NG8, gl8 = t - i * NG8;
            const unsigned* base = S + i * 64 + 8 * gl8;
            unsigned d[14];
            *(uint4*)&d[0]  = *(const uint4*)(base);
            *(uint4*)&d[4]  = *(const uint4*)(base + 4);
            *(uint4*)&d[8]  = *(const uint4*)(base + 8);
            *(uint2*)&d[12] = *(const uint2*)(base + 12);
            float W[26];
#pragma unroll
            for (int c = 0; c < 26; ++c) {
                const int D = ((c >> 3) << 2) + (c & 3);
                v2 f = up16(d[D]);
                W[c] = ((c >> 2) & 1) ? f.y : f.x;
            }
            v2 U[18];                                // U[t] = (col t, col t+8)
#pragma unroll
            for (int u = 0; u < 18; ++u)
                U[u] = (v2){ W[u], W[u + 8] };
            v2 q[4];
#pragma unroll
            for (int m = 0; m < 4; ++m) {
                v2 a = U[2 * m + 11] * fd[0];
#pragma unroll
                for (int u = 1; u < 12; ++u)
                    a += U[2 * m + 11 - u] * fd[u];
                q[m] = a;
            }
            const int g8g = GO8 + gl8;
            float* orow = o + (size_t)(i0 + i) * OUT_HW + 8 * g8g;
            *(float4*)(orow) = make_float4(q[0].x, q[1].x, q[2].x, q[3].x);
            if (g8g < 18)
                *(float4*)(orow + 4) = make_float4(q[0].y, q[1].y, q[2].y, q[3].y);
        }
    }
}

__global__ __launch_bounds__(256, 4) void afa_wave(
    const float* __restrict__ x, const float* __restrict__ ku,
    const float* __restrict__ kd, float* __restrict__ out)
{
    __shared__ __align__(16) unsigned sb[4 * 1024];    // 16 KB: 4 wave slices
    const int lt = threadIdx.x;
    const int w  = lt >> 6;
    const int l  = lt & 63;
    unsigned* S = sb + (w << 10);

    const int unit = blockIdx.x * 4 + w;               // 0..15359
    const int pz   = unit / 30;
    const int rem  = unit - 30 * pz;
    const int band = rem / 3;
    const int chunk = rem - 3 * band;
    const int i0   = (band == 9) ? 132 : 16 * band;
    const int IR0  = (i0 >> 1) + 1;

    float fu[24], fd[12];
#pragma unroll
    for (int i = 0; i < 24; ++i) fu[i] = rfl(ku[i]);
#pragma unroll
    for (int i = 0; i < 12; ++i) fd[i] = rfl(kd[i]);

    const float* xin = x + (size_t)pz * (IN_HW * IN_HW);
    float* o = out + (size_t)pz * (OUT_HW * OUT_HW);

    if (chunk == 0)      wave_body<0>(xin, o, S, l, i0, IR0, fu, fd);
    else if (chunk == 1) wave_body<1>(xin, o, S, l, i0, IR0, fu, fd);
    else                 wave_body<2>(xin, o, S, l, i0, IR0, fu, fd);
}

extern "C" void kernel_launch(void* const* d_in, const int* in_sizes, int n_in,
                              void* d_out, int out_size, void* d_ws, size_t ws_size,
                              hipStream_t stream) {
    const float* x  = (const float*)d_in[0];
    const float* ku = (const float*)d_in[1];
    const float* kd = (const float*)d_in[2];
    float* out = (float*)d_out;
    afa_wave<<<dim3(3840), dim3(256), 0, stream>>>(x, ku, kd, out);
}

// Round 17
// 39.427 us; speedup vs baseline: 1.0069x; 1.0069x over previous
//
#include <hip/hip_runtime.h>
#include <hip/hip_fp16.h>

// AliasFreeActivation, round 17: r13 barrier-free wave-private units with
// P2's column values PINNED in VGPRs via empty inline-asm "+v" operands.
// Diagnosis: VGPR_Count=32 across r13-r16 is impossible with colv+acc (64
// VGPRs) live -> the compiler was REMATERIALIZING colv from LDS (re-issuing
// ds_read before each use, ~250/lane instead of 16) -> LDS-pipe saturation
// (~36us/CU at 5.8cyc/ds_read_b32) = the conserved "stall". The asm pin
// makes remat illegal (asm may clobber the value).
// x (2,256,84,84) f32 -> up x4 (24t) -> lrelu -> down x2 (12t) -> crop 10
// -> out (2,256,148,148) f32.
//
// Unit = (plane pz, band b 0..9, chunk c 0..2) per wave64, private 1024-dw
// LDS slice, no __syncthreads. Band: out rows i0..i0+15, i0=min(16b,132)
// (band 9 overlaps band 8; duplicate stores bitwise-identical).
// Chunks: c0 g0..15 / out g8 0..6; c1 g14..29 / g8 7..13; c2 g28..38 / g8 14..18.
// LDS f16 layout: row r, 64 dwords; dword 4B+cc = half2(col 8B+cc, col 8B+4+cc).
// P2: lane-per-dword fused up-v+lrelu+down-v, v2 f32 math, lane-local alias.
// Cross-lane handoffs ordered by s_waitcnt lgkmcnt(0) (lockstep wave).

typedef float v2 __attribute__((ext_vector_type(2)));

constexpr int IN_HW  = 84;
constexpr int OUT_HW = 148;
constexpr float SLOPE = 0.2f;

__device__ __forceinline__ float rfl(float v) {
    return __uint_as_float(__builtin_amdgcn_readfirstlane(__float_as_uint(v)));
}
__device__ __forceinline__ unsigned pkv(v2 a) {
    __half2 h = __float22half2_rn(make_float2(a.x, a.y));
    union { __half2 h; unsigned u; } c; c.h = h; return c.u;
}
__device__ __forceinline__ v2 up16(unsigned u) {
    union { unsigned u; __half2 h; } c; c.u = u;
    float2 f = __half22float2(c.h);
    return (v2){f.x, f.y};
}
__device__ __forceinline__ void lds_fence() {
    asm volatile("s_waitcnt lgkmcnt(0)" ::: "memory");
}

template<int CHUNK>
__device__ __forceinline__ void wave_body(
    const float* __restrict__ xin, float* __restrict__ o,
    unsigned* __restrict__ S, int l, int i0, int IR0,
    const float* fu, const float* fd)
{
    constexpr int G0  = (CHUNK == 0) ? 0 : (CHUNK == 1) ? 14 : 28;
    constexpr int NG  = (CHUNK == 2) ? 11 : 16;   // input col-groups
    constexpr int GO8 = (CHUNK == 0) ? 0 : (CHUNK == 1) ? 7 : 14;
    constexpr int NG8 = (CHUNK == 2) ? 5 : 7;     // output col-groups
    constexpr int NT1 = 16 * NG;
    constexpr int NT3 = 16 * NG8;

    // ---- P1: horizontal up-conv into private LDS slice ----
#pragma unroll
    for (int k = 0; k < (NT1 + 63) / 64; ++k) {
        int t = l + 64 * k;
        if (t < NT1) {
            int r = t / NG, gl = t - r * NG, g = G0 + gl;
            const float* xr = xin + (IR0 + r) * IN_HW + 2 * g;
            float2 p0 = *(const float2*)(xr);
            float2 p1 = *(const float2*)(xr + 2);
            float2 p2 = *(const float2*)(xr + 4);
            float2 p3 = *(const float2*)(xr + 6);
            float2 p4 = *(const float2*)(xr + ((g == 38) ? 6 : 8)); // OOB guard
            v2 V0 = {p0.y, p1.x};
            v2 V1 = {p1.x, p1.y};
            v2 V2 = {p1.y, p2.x};
            v2 V3 = {p2.x, p2.y};
            v2 V4 = {p2.y, p3.x};
            v2 V5 = {p3.x, p3.y};
            v2 V6 = {p3.y, p4.x};   // .y garbage only for g=38 tail (unused cols)
            v2 AB0 = V5*fu[1] + V4*fu[5] + V3*fu[9]  + V2*fu[13] + V1*fu[17] + V0*fu[21];
            v2 AB1 = V5*fu[2] + V4*fu[6] + V3*fu[10] + V2*fu[14] + V1*fu[18] + V0*fu[22];
            v2 AB2 = V5*fu[3] + V4*fu[7] + V3*fu[11] + V2*fu[15] + V1*fu[19] + V0*fu[23];
            v2 AB3 = V6*fu[0] + V5*fu[4] + V4*fu[8]  + V3*fu[12] + V2*fu[16] + V1*fu[20];
            uint4 pk;
            pk.x = pkv(AB0); pk.y = pkv(AB1); pk.z = pkv(AB2); pk.w = pkv(AB3);
            *(uint4*)(S + r * 64 + 4 * gl) = pk;
        }
    }
    lds_fence();                       // P1 writes visible to all lanes

    // ---- P2: lane-per-dword fused up-v + lrelu + down-v (v2 f32) ----
    {
        const unsigned* up = S + l;
        v2 colv[16];
#pragma unroll
        for (int r = 0; r < 16; ++r) colv[r] = up16(up[r * 64]);
        // PIN: each colv value must live in VGPRs; LDS remat now illegal.
#pragma unroll
        for (int r = 0; r < 16; ++r)
            asm volatile("" : "+v"(colv[r]));
        v2 acc[16];
#pragma unroll
        for (int i = 0; i < 16; ++i) acc[i] = (v2)(0.0f);
#pragma unroll
        for (int t = 0; t < 42; ++t) {
            const int n  = (t + 1) >> 2;
            const int ph = (t + 1) & 3;
            v2 z = colv[n+5] * fu[ph];
            z += colv[n+4] * fu[ph+4];
            z += colv[n+3] * fu[ph+8];
            z += colv[n+2] * fu[ph+12];
            z += colv[n+1] * fu[ph+16];
            z += colv[n]   * fu[ph+20];
            z = __builtin_elementwise_max(z, z * SLOPE);   // lrelu
            const int m = t >> 1;
#pragma unroll
            for (int k = 0; k < 6; ++k) {                  // static after unroll
                const int li = m - k;
                if (li >= 0 && li < 16)
                    acc[li] += z * fd[(t & 1) ? (10 - 2*k) : (11 - 2*k)];
            }
        }
        unsigned* tvc = S + l;          // same dwords this lane read: no hazard
#pragma unroll
        for (int i = 0; i < 16; ++i) tvc[i * 64] = pkv(acc[i]);
    }
    lds_fence();                       // P2 writes visible to all lanes

    // ---- P3: horizontal down-conv + store ----
#pragma unroll
    for (int k = 0; k < 2; ++k) {
        int t = l + 64 * k;
        if (t < NT3) {
            int i = t / NG8, gl8 = t - i * NG8;
            const unsigned* base = S + i * 64 + 8 * gl8;
            unsigned d[14];
            *(uint4*)&d[0]  = *(const uint4*)(base);
            *(uint4*)&d[4]  = *(const uint4*)(base + 4);
            *(uint4*)&d[8]  = *(const uint4*)(base + 8);
            *(uint2*)&d[12] = *(const uint2*)(base + 12);
            float W[26];
#pragma unroll
            for (int c = 0; c < 26; ++c) {
                const int D = ((c >> 3) << 2) + (c & 3);
                v2 f = up16(d[D]);
                W[c] = ((c >> 2) & 1) ? f.y : f.x;
            }
            v2 U[18];                                // U[t] = (col t, col t+8)
#pragma unroll
            for (int u = 0; u < 18; ++u)
                U[u] = (v2){ W[u], W[u + 8] };
            v2 q[4];
#pragma unroll
            for (int m = 0; m < 4; ++m) {
                v2 a = U[2 * m + 11] * fd[0];
#pragma unroll
                for (int u = 1; u < 12; ++u)
                    a += U[2 * m + 11 - u] * fd[u];
                q[m] = a;
            }
            const int g8g = GO8 + gl8;
            float* orow = o + (size_t)(i0 + i) * OUT_HW + 8 * g8g;
            *(float4*)(orow) = make_float4(q[0].x, q[1].x, q[2].x, q[3].x);
            if (g8g < 18)
                *(float4*)(orow + 4) = make_float4(q[0].y, q[1].y, q[2].y, q[3].y);
        }
    }
}

__global__ __launch_bounds__(256, 4) void afa_wave(
    const float* __restrict__ x, const float* __restrict__ ku,
    const float* __restrict__ kd, float* __restrict__ out)
{
    __shared__ __align__(16) unsigned sb[4 * 1024];    // 16 KB: 4 wave slices
    const int lt = threadIdx.x;
    const int w  = lt >> 6;
    const int l  = lt & 63;
    unsigned* S = sb + (w << 10);

    const int unit = blockIdx.x * 4 + w;               // 0..15359
    const int pz   = unit / 30;
    const int rem  = unit - 30 * pz;
    const int band = rem / 3;
    const int chunk = rem - 3 * band;
    const int i0   = (band == 9) ? 132 : 16 * band;
    const int IR0  = (i0 >> 1) + 1;

    float fu[24], fd[12];
#pragma unroll
    for (int i = 0; i < 24; ++i) fu[i] = rfl(ku[i]);
#pragma unroll
    for (int i = 0; i < 12; ++i) fd[i] = rfl(kd[i]);

    const float* xin = x + (size_t)pz * (IN_HW * IN_HW);
    float* o = out + (size_t)pz * (OUT_HW * OUT_HW);

    if (chunk == 0)      wave_body<0>(xin, o, S, l, i0, IR0, fu, fd);
    else if (chunk == 1) wave_body<1>(xin, o, S, l, i0, IR0, fu, fd);
    else                 wave_body<2>(xin, o, S, l, i0, IR0, fu, fd);
}

extern "C" void kernel_launch(void* const* d_in, const int* in_sizes, int n_in,
                              void* d_out, int out_size, void* d_ws, size_t ws_size,
                              hipStream_t stream) {
    const float* x  = (const float*)d_in[0];
    const float* ku = (const float*)d_in[1];
    const float* kd = (const float*)d_in[2];
    float* out = (float*)d_out;
    afa_wave<<<dim3(3840), dim3(256), 0, stream>>>(x, ku, kd, out);
}